// Round 5
// baseline (1594.894 us; speedup 1.0000x reference)
//
#include <hip/hip_runtime.h>
#include <hip/hip_bf16.h>

#define NN 100000
#define NE 1600000
#define BN_EPS 1e-5f
#define NB 391                                      // ceil(NN/256) for scan
#define NBKT 782                                    // ceil(NN/128) dst buckets
#define BCAP 512                                    // per (region,bucket) capacity; mean 256

typedef __attribute__((ext_vector_type(8))) short bf16x8;
typedef __attribute__((ext_vector_type(4))) float f32x4;

static __device__ __forceinline__ ushort f2b(float f) {
  __hip_bfloat16 h = __float2bfloat16(f);            // RNE
  return __builtin_bit_cast(ushort, h);
}
static __device__ __forceinline__ float blo(uint v) { return __builtin_bit_cast(float, v << 16); }
static __device__ __forceinline__ float bhi(uint v) { return __builtin_bit_cast(float, v & 0xFFFF0000u); }

// ---------------- CSR build, pass A: degree count + region-binned edges ----------------
// region = blockIdx&7 ~= XCD (round-robin dispatch): sequential slots in a region are
// written from one XCD's L2 -> full-line merges (fixes 64B/edge partial writebacks).
__global__ __launch_bounds__(256) void k_bin(const int* __restrict__ ei, int* __restrict__ deg,
                                             int* __restrict__ bfill, uint* __restrict__ binned) {
  const int e = blockIdx.x * 256 + threadIdx.x;      // grid covers NE exactly
  const int s = ei[e];
  const int d = ei[NE + e];
  atomicAdd(&deg[d], 1);
  const int bucket = d >> 7;
  const int idx = (blockIdx.x & 7) * NBKT + bucket;
  const int pos = atomicAdd(&bfill[idx], 1);
  binned[(size_t)idx * BCAP + pos] = ((uint)(d & 127) << 17) | (uint)s;
}

__global__ __launch_bounds__(256) void k_dinv(const int* __restrict__ deg, float* __restrict__ dinv) {
  int v = blockIdx.x * 256 + threadIdx.x;
  if (v < NN) dinv[v] = rsqrtf((float)deg[v] + 1.0f);
}

// level 1: per-block sums of deg
__global__ __launch_bounds__(256) void k_scan1(const int* __restrict__ deg, int* __restrict__ bsum) {
  __shared__ int lds[256];
  const int t = threadIdx.x;
  const int i = blockIdx.x * 256 + t;
  lds[t] = (i < NN) ? deg[i] : 0;
  __syncthreads();
  for (int d = 128; d > 0; d >>= 1) {
    if (t < d) lds[t] += lds[t + d];
    __syncthreads();
  }
  if (t == 0) bsum[blockIdx.x] = lds[0];
}

// level 2: scan the NB block sums
__global__ __launch_bounds__(512) void k_scan2(const int* __restrict__ bsum, int* __restrict__ boff,
                                               int* __restrict__ rp) {
  __shared__ int lds[512];
  const int t = threadIdx.x;
  const int own = (t < NB) ? bsum[t] : 0;
  lds[t] = own;
  __syncthreads();
  for (int d = 1; d < 512; d <<= 1) {
    int v = (t >= d) ? lds[t - d] : 0;
    __syncthreads();
    lds[t] += v;
    __syncthreads();
  }
  if (t < NB) boff[t] = lds[t] - own;
  if (t == 511) rp[NN] = lds[511];
}

// level 3: in-block exclusive scan + block offset
__global__ __launch_bounds__(256) void k_scan3(const int* __restrict__ deg, const int* __restrict__ boff,
                                               int* __restrict__ rp) {
  __shared__ int lds[256];
  const int t = threadIdx.x;
  const int i = blockIdx.x * 256 + t;
  const int own = (i < NN) ? deg[i] : 0;
  lds[t] = own;
  __syncthreads();
  for (int d = 1; d < 256; d <<= 1) {
    int v = (t >= d) ? lds[t - d] : 0;
    __syncthreads();
    lds[t] += v;
    __syncthreads();
  }
  if (i < NN) rp[i] = boff[blockIdx.x] + lds[t] - own;
}

// ---------------- CSR build, pass B: per-bucket fine scatter (one block/bucket) ----------------
__global__ __launch_bounds__(256) void k_scatter2(const uint* __restrict__ binned,
                                                  const int* __restrict__ bfill,
                                                  const int* __restrict__ rp, int* __restrict__ csr) {
  __shared__ int lfill[128];
  __shared__ int lrp[128];
  const int t = threadIdx.x;
  const int bucket = blockIdx.x;
  const int v0 = bucket << 7;
  if (t < 128) {
    lfill[t] = 0;
    lrp[t] = (v0 + t < NN) ? rp[v0 + t] : 0;
  }
  __syncthreads();
  #pragma unroll
  for (int r = 0; r < 8; ++r) {
    const int idx = r * NBKT + bucket;
    const int c = bfill[idx];
    const uint* seg = binned + (size_t)idx * BCAP;
    for (int j = t; j < c; j += 256) {
      const uint u = seg[j];
      const int ld = u >> 17;
      const int s = (int)(u & 0x1FFFFu);
      const int pos = lrp[ld] + atomicAdd(&lfill[ld], 1);
      csr[pos] = s;
    }
  }
}

// ---------------- W prep: wt[layer][n][k] = bf16(W[k][n]) ----------------
__global__ __launch_bounds__(128) void k_wt(const float* __restrict__ W0, const float* __restrict__ W1,
                                            const float* __restrict__ W2, ushort* __restrict__ wt) {
  const int lay = blockIdx.y, n = blockIdx.x, k = threadIdx.x;
  const float* W = (lay == 0) ? W0 : (lay == 1) ? W1 : W2;
  wt[lay * 16384 + n * 128 + k] = f2b(W[k * 128 + n]);
}

// ---------------- GEMM (MFMA bf16) with fused input BN-affine+ReLU ----------------
// hw = bf16(relu(sc*h + sh)) @ W   (aff=0: plain h @ W, no relu)
__global__ __launch_bounds__(256) void k_gemm(const float* __restrict__ hf,
                                              const ushort* __restrict__ wt,   // [n][k] bf16
                                              const float* __restrict__ sc, const float* __restrict__ sh,
                                              const int aff,
                                              ushort* __restrict__ hw) {
  __shared__ ushort wlds[128 * 128];                 // 32 KiB
  __shared__ float scs[128], shs[128];
  const int t = threadIdx.x;
  {
    const uint4* src = (const uint4*)wt;
    uint4* dst = (uint4*)wlds;
    #pragma unroll
    for (int i = 0; i < 8; ++i) {
      int idx = t + i * 256;
      int n = idx >> 4;
      dst[idx ^ (n & 7)] = src[idx];
    }
  }
  if (t < 128) { scs[t] = aff ? sc[t] : 1.0f; shs[t] = aff ? sh[t] : 0.0f; }
  __syncthreads();

  const int wv = t >> 6, l = t & 63;
  const int lr = l & 15, lk = l >> 4;
  const int row0 = blockIdx.x * 128 + wv * 32;
  f32x4 acc[2][8] = {};
  const uint4* wchunks = (const uint4*)wlds;

  #pragma unroll
  for (int kb = 0; kb < 4; ++kb) {
    const int k0 = kb * 32 + lk * 8;
    const float4 s4a = *(const float4*)(scs + k0);
    const float4 s4b = *(const float4*)(scs + k0 + 4);
    const float4 h4a = *(const float4*)(shs + k0);
    const float4 h4b = *(const float4*)(shs + k0 + 4);
    const int r0 = min(row0 + lr, NN - 1);
    const int r1 = min(row0 + 16 + lr, NN - 1);
    bf16x8 a0, a1;
    #pragma unroll
    for (int rr = 0; rr < 2; ++rr) {
      const int r = rr ? r1 : r0;
      const float4 p = *(const float4*)(hf + (size_t)r * 128 + k0);
      const float4 q = *(const float4*)(hf + (size_t)r * 128 + k0 + 4);
      float u0 = fmaf(s4a.x, p.x, h4a.x), u1 = fmaf(s4a.y, p.y, h4a.y);
      float u2 = fmaf(s4a.z, p.z, h4a.z), u3 = fmaf(s4a.w, p.w, h4a.w);
      float u4 = fmaf(s4b.x, q.x, h4b.x), u5 = fmaf(s4b.y, q.y, h4b.y);
      float u6 = fmaf(s4b.z, q.z, h4b.z), u7 = fmaf(s4b.w, q.w, h4b.w);
      if (aff) {
        u0 = fmaxf(u0, 0.f); u1 = fmaxf(u1, 0.f); u2 = fmaxf(u2, 0.f); u3 = fmaxf(u3, 0.f);
        u4 = fmaxf(u4, 0.f); u5 = fmaxf(u5, 0.f); u6 = fmaxf(u6, 0.f); u7 = fmaxf(u7, 0.f);
      }
      bf16x8 a;
      a[0] = (short)f2b(u0); a[1] = (short)f2b(u1); a[2] = (short)f2b(u2); a[3] = (short)f2b(u3);
      a[4] = (short)f2b(u4); a[5] = (short)f2b(u5); a[6] = (short)f2b(u6); a[7] = (short)f2b(u7);
      if (rr) a1 = a; else a0 = a;
    }
    #pragma unroll
    for (int nt = 0; nt < 8; ++nt) {
      const int n = nt * 16 + lr;
      const int chunk = n * 16 + ((kb * 4 + lk) ^ (n & 7));
      const bf16x8 b = *(const bf16x8*)(wchunks + chunk);
      acc[0][nt] = __builtin_amdgcn_mfma_f32_16x16x32_bf16(a0, b, acc[0][nt], 0, 0, 0);
      acc[1][nt] = __builtin_amdgcn_mfma_f32_16x16x32_bf16(a1, b, acc[1][nt], 0, 0, 0);
    }
  }
  #pragma unroll
  for (int rt = 0; rt < 2; ++rt)
    #pragma unroll
    for (int j = 0; j < 4; ++j) {
      const int row = row0 + rt * 16 + lk * 4 + j;
      if (row < NN) {
        #pragma unroll
        for (int nt = 0; nt < 8; ++nt)
          hw[(size_t)row * 128 + nt * 16 + lr] = f2b(acc[rt][nt][j]);
      }
    }
}

// ---------------- aggregation + fused BN-stats ----------------
// 2 nodes per wave (32 lanes x 4 features = 8B/lane), unroll 4 -> 8 row-gathers in flight.
__global__ __launch_bounds__(256) void k_agg(const ushort* __restrict__ hw,
                                             const int* __restrict__ rp, const int* __restrict__ csr,
                                             const float* __restrict__ dinv, const float* __restrict__ bias,
                                             float* __restrict__ out, float* __restrict__ stats) {
  __shared__ float ss[8][128], sq[8][128];           // 8 KiB
  const int t = threadIdx.x;
  const int gw = (blockIdx.x * 256 + t) >> 6;        // global wave id
  const int half = (t >> 5) & 1, l32 = t & 31;
  const int v = gw * 2 + half;                       // grid covers NN exactly (12500*8)
  const int beg = rp[v], end = rp[v + 1];
  float a0 = 0.f, a1 = 0.f, a2 = 0.f, a3 = 0.f;
  int i = beg;
  for (; i + 4 <= end; i += 4) {
    const int s0 = __builtin_nontemporal_load(csr + i);
    const int s1 = __builtin_nontemporal_load(csr + i + 1);
    const int s2 = __builtin_nontemporal_load(csr + i + 2);
    const int s3 = __builtin_nontemporal_load(csr + i + 3);
    const float d0 = dinv[s0], d1 = dinv[s1], d2 = dinv[s2], d3 = dinv[s3];
    const uint2 w0 = *(const uint2*)(hw + (size_t)s0 * 128 + l32 * 4);
    const uint2 w1 = *(const uint2*)(hw + (size_t)s1 * 128 + l32 * 4);
    const uint2 w2 = *(const uint2*)(hw + (size_t)s2 * 128 + l32 * 4);
    const uint2 w3 = *(const uint2*)(hw + (size_t)s3 * 128 + l32 * 4);
    a0 = fmaf(d0, blo(w0.x), a0); a1 = fmaf(d0, bhi(w0.x), a1);
    a2 = fmaf(d0, blo(w0.y), a2); a3 = fmaf(d0, bhi(w0.y), a3);
    a0 = fmaf(d1, blo(w1.x), a0); a1 = fmaf(d1, bhi(w1.x), a1);
    a2 = fmaf(d1, blo(w1.y), a2); a3 = fmaf(d1, bhi(w1.y), a3);
    a0 = fmaf(d2, blo(w2.x), a0); a1 = fmaf(d2, bhi(w2.x), a1);
    a2 = fmaf(d2, blo(w2.y), a2); a3 = fmaf(d2, bhi(w2.y), a3);
    a0 = fmaf(d3, blo(w3.x), a0); a1 = fmaf(d3, bhi(w3.x), a1);
    a2 = fmaf(d3, blo(w3.y), a2); a3 = fmaf(d3, bhi(w3.y), a3);
  }
  for (; i < end; ++i) {
    const int s = __builtin_nontemporal_load(csr + i);
    const float ds = dinv[s];
    const uint2 wv2 = *(const uint2*)(hw + (size_t)s * 128 + l32 * 4);
    a0 = fmaf(ds, blo(wv2.x), a0); a1 = fmaf(ds, bhi(wv2.x), a1);
    a2 = fmaf(ds, blo(wv2.y), a2); a3 = fmaf(ds, bhi(wv2.y), a3);
  }
  const float dv = dinv[v];
  const uint2 sw = *(const uint2*)(hw + (size_t)v * 128 + l32 * 4);
  const float4 bb = *(const float4*)(bias + l32 * 4);
  const float dv2 = dv * dv;
  float4 o;
  o.x = fmaf(a0, dv, fmaf(blo(sw.x), dv2, bb.x));
  o.y = fmaf(a1, dv, fmaf(bhi(sw.x), dv2, bb.y));
  o.z = fmaf(a2, dv, fmaf(blo(sw.y), dv2, bb.z));
  o.w = fmaf(a3, dv, fmaf(bhi(sw.y), dv2, bb.w));
  *(float4*)(out + (size_t)v * 128 + l32 * 4) = o;

  // fused BN stats: per-block reduce, one atomic per feature per block
  const int h8 = t >> 5;                             // half-wave 0..7
  const int f0 = l32 * 4;
  ss[h8][f0 + 0] = o.x; ss[h8][f0 + 1] = o.y; ss[h8][f0 + 2] = o.z; ss[h8][f0 + 3] = o.w;
  sq[h8][f0 + 0] = o.x * o.x; sq[h8][f0 + 1] = o.y * o.y;
  sq[h8][f0 + 2] = o.z * o.z; sq[h8][f0 + 3] = o.w * o.w;
  __syncthreads();
  if (t < 128) {
    float s = 0.f;
    #pragma unroll
    for (int r = 0; r < 8; ++r) s += ss[r][t];
    atomicAdd(&stats[t], s);
  } else {
    const int f = t - 128;
    float s = 0.f;
    #pragma unroll
    for (int r = 0; r < 8; ++r) s += sq[r][f];
    atomicAdd(&stats[128 + f], s);
  }
}

__global__ void k_bnfin(const float* __restrict__ stats, const float* __restrict__ gamma,
                        const float* __restrict__ beta, float* __restrict__ sc, float* __restrict__ sh) {
  const int c = threadIdx.x;
  const float inv_n = 1.0f / (float)NN;
  const float mean = stats[c] * inv_n;
  const float var = fmaxf(stats[128 + c] * inv_n - mean * mean, 0.f);
  const float k = gamma[c] * rsqrtf(var + BN_EPS);
  sc[c] = k;
  sh[c] = fmaf(-mean, k, beta[c]);
}

// final layer only: BN+relu in place on fp32 output
__global__ __launch_bounds__(256) void k_bnfinal(float* __restrict__ h,
                                                 const float* __restrict__ sc, const float* __restrict__ sh) {
  const int i = blockIdx.x * 256 + threadIdx.x;      // grid covers NN*128/4 exactly
  const int c = (i & 31) * 4;
  float4 v = ((const float4*)h)[i];
  v.x = fmaxf(fmaf(sc[c + 0], v.x, sh[c + 0]), 0.f);
  v.y = fmaxf(fmaf(sc[c + 1], v.y, sh[c + 1]), 0.f);
  v.z = fmaxf(fmaf(sc[c + 2], v.z, sh[c + 2]), 0.f);
  v.w = fmaxf(fmaf(sc[c + 3], v.w, sh[c + 3]), 0.f);
  ((float4*)h)[i] = v;
}

// ---------------- launch ----------------
extern "C" void kernel_launch(void* const* d_in, const int* in_sizes, int n_in,
                              void* d_out, int out_size, void* d_ws, size_t ws_size,
                              hipStream_t stream) {
  const float* x  = (const float*)d_in[0];
  const int*   ei = (const int*)d_in[1];
  const float* W[3]  = {(const float*)d_in[2],  (const float*)d_in[6],  (const float*)d_in[10]};
  const float* b[3]  = {(const float*)d_in[3],  (const float*)d_in[7],  (const float*)d_in[11]};
  const float* g[3]  = {(const float*)d_in[4],  (const float*)d_in[8],  (const float*)d_in[12]};
  const float* be[3] = {(const float*)d_in[5],  (const float*)d_in[9],  (const float*)d_in[13]};

  char* ws = (char*)d_ws;
  ushort* hwb    = (ushort*)(ws);               // NN*128 bf16 = 25,600,000 B
  uint*   binned = (uint*)(ws);                 // overlay: 8*NBKT*BCAP*4 = 12,812,288 B (dead before gemm)
  int*    bfill  = (int*)(ws + 13000000);       // 8*NBKT*4 = 25,024 B (dead before gemm)
  int*    csr    = (int*)(ws + 51200000);       // NE ints
  int*    deg    = (int*)(ws + 57600000);
  int*    rp     = (int*)(ws + 58000000);
  float*  dinv   = (float*)(ws + 58400016);
  ushort* wtb    = (ushort*)(ws + 58800016);    // 3 x 128x128 bf16 (W^T)
  float*  stats  = (float*)(ws + 58898320);
  float*  sc     = (float*)(ws + 58899344);
  float*  sh     = (float*)(ws + 58899856);
  int*    bsum   = (int*)(ws + 58900368);       // NB ints
  int*    boff   = (int*)(ws + 58901936);       // NB ints
  float*  hbuf   = (float*)d_out;               // fp32 agg output (pre-BN), also final output

  hipMemsetAsync(deg, 0, NN * 4, stream);
  hipMemsetAsync(bfill, 0, 8 * NBKT * 4, stream);
  k_bin<<<NE / 256, 256, 0, stream>>>(ei, deg, bfill, binned);
  k_dinv<<<(NN + 255) / 256, 256, 0, stream>>>(deg, dinv);
  k_scan1<<<NB, 256, 0, stream>>>(deg, bsum);
  k_scan2<<<1, 512, 0, stream>>>(bsum, boff, rp);
  k_scan3<<<NB, 256, 0, stream>>>(deg, boff, rp);
  k_scatter2<<<NBKT, 256, 0, stream>>>(binned, bfill, rp, csr);
  k_wt<<<dim3(128, 3), 128, 0, stream>>>(W[0], W[1], W[2], wtb);

  for (int L = 0; L < 3; ++L) {
    const float* hin = (L == 0) ? x : hbuf;
    k_gemm<<<(NN + 127) / 128, 256, 0, stream>>>(hin, wtb + L * 16384, sc, sh, (L > 0) ? 1 : 0, hwb);
    hipMemsetAsync(stats, 0, 256 * 4, stream);
    k_agg<<<12500, 256, 0, stream>>>(hwb, rp, csr, dinv, b[L], hbuf, stats);
    k_bnfin<<<1, 128, 0, stream>>>(stats, g[L], be[L], sc, sh);
  }
  k_bnfinal<<<NN * 128 / 1024, 256, 0, stream>>>(hbuf, sc, sh);
}

// Round 7
// 662.545 us; speedup vs baseline: 2.4072x; 2.4072x over previous
//
#include <hip/hip_runtime.h>
#include <hip/hip_bf16.h>

#define NN 100000
#define NE 1600000
#define BN_EPS 1e-5f
#define NB 391                                      // ceil(NN/256) for scan
#define NBKT 782                                    // ceil(NN/128) dst buckets
#define BCAP 512                                    // per (region,bucket) capacity; mean 256

typedef __attribute__((ext_vector_type(8))) short bf16x8;
typedef __attribute__((ext_vector_type(4))) float f32x4;

static __device__ __forceinline__ ushort f2b(float f) {
  __hip_bfloat16 h = __float2bfloat16(f);            // RNE
  return __builtin_bit_cast(ushort, h);
}
static __device__ __forceinline__ float blo(uint v) { return __builtin_bit_cast(float, v << 16); }
static __device__ __forceinline__ float bhi(uint v) { return __builtin_bit_cast(float, v & 0xFFFF0000u); }

// ---------------- CSR build, pass A: degree count + region-binned edges ----------------
// region = blockIdx&7 ~= XCD (round-robin dispatch): sequential slots in a region are
// written from one XCD's L2 -> full-line merges (fixes 64B/edge partial writebacks).
__global__ __launch_bounds__(256) void k_bin(const int* __restrict__ ei, int* __restrict__ deg,
                                             int* __restrict__ bfill, uint* __restrict__ binned) {
  const int e = blockIdx.x * 256 + threadIdx.x;      // grid covers NE exactly
  const int s = ei[e];
  const int d = ei[NE + e];
  atomicAdd(&deg[d], 1);
  const int bucket = d >> 7;
  const int idx = (blockIdx.x & 7) * NBKT + bucket;
  const int pos = atomicAdd(&bfill[idx], 1);
  binned[(size_t)idx * BCAP + pos] = ((uint)(d & 127) << 17) | (uint)s;
}

__global__ __launch_bounds__(256) void k_dinv(const int* __restrict__ deg, float* __restrict__ dinv) {
  int v = blockIdx.x * 256 + threadIdx.x;
  if (v < NN) dinv[v] = rsqrtf((float)deg[v] + 1.0f);
}

// level 1: per-block sums of deg
__global__ __launch_bounds__(256) void k_scan1(const int* __restrict__ deg, int* __restrict__ bsum) {
  __shared__ int lds[256];
  const int t = threadIdx.x;
  const int i = blockIdx.x * 256 + t;
  lds[t] = (i < NN) ? deg[i] : 0;
  __syncthreads();
  for (int d = 128; d > 0; d >>= 1) {
    if (t < d) lds[t] += lds[t + d];
    __syncthreads();
  }
  if (t == 0) bsum[blockIdx.x] = lds[0];
}

// level 2: scan the NB block sums
__global__ __launch_bounds__(512) void k_scan2(const int* __restrict__ bsum, int* __restrict__ boff,
                                               int* __restrict__ rp) {
  __shared__ int lds[512];
  const int t = threadIdx.x;
  const int own = (t < NB) ? bsum[t] : 0;
  lds[t] = own;
  __syncthreads();
  for (int d = 1; d < 512; d <<= 1) {
    int v = (t >= d) ? lds[t - d] : 0;
    __syncthreads();
    lds[t] += v;
    __syncthreads();
  }
  if (t < NB) boff[t] = lds[t] - own;
  if (t == 511) rp[NN] = lds[511];
}

// level 3: in-block exclusive scan + block offset
__global__ __launch_bounds__(256) void k_scan3(const int* __restrict__ deg, const int* __restrict__ boff,
                                               int* __restrict__ rp) {
  __shared__ int lds[256];
  const int t = threadIdx.x;
  const int i = blockIdx.x * 256 + t;
  const int own = (i < NN) ? deg[i] : 0;
  lds[t] = own;
  __syncthreads();
  for (int d = 1; d < 256; d <<= 1) {
    int v = (t >= d) ? lds[t - d] : 0;
    __syncthreads();
    lds[t] += v;
    __syncthreads();
  }
  if (i < NN) rp[i] = boff[blockIdx.x] + lds[t] - own;
}

// ---------------- CSR build, pass B: per-bucket fine scatter (one block/bucket) ----------------
__global__ __launch_bounds__(256) void k_scatter2(const uint* __restrict__ binned,
                                                  const int* __restrict__ bfill,
                                                  const int* __restrict__ rp, int* __restrict__ csr) {
  __shared__ int lfill[128];
  __shared__ int lrp[128];
  const int t = threadIdx.x;
  const int bucket = blockIdx.x;
  const int v0 = bucket << 7;
  if (t < 128) {
    lfill[t] = 0;
    lrp[t] = (v0 + t < NN) ? rp[v0 + t] : 0;
  }
  __syncthreads();
  #pragma unroll
  for (int r = 0; r < 8; ++r) {
    const int idx = r * NBKT + bucket;
    const int c = bfill[idx];
    const uint* seg = binned + (size_t)idx * BCAP;
    for (int j = t; j < c; j += 256) {
      const uint u = seg[j];
      const int ld = u >> 17;
      const int s = (int)(u & 0x1FFFFu);
      const int pos = lrp[ld] + atomicAdd(&lfill[ld], 1);
      csr[pos] = s;
    }
  }
}

// ---------------- W prep: wt[layer][n][k] = bf16(W[k][n]) ----------------
__global__ __launch_bounds__(128) void k_wt(const float* __restrict__ W0, const float* __restrict__ W1,
                                            const float* __restrict__ W2, ushort* __restrict__ wt) {
  const int lay = blockIdx.y, n = blockIdx.x, k = threadIdx.x;
  const float* W = (lay == 0) ? W0 : (lay == 1) ? W1 : W2;
  wt[lay * 16384 + n * 128 + k] = f2b(W[k * 128 + n]);
}

// ---------------- GEMM (MFMA bf16) with fused input BN-affine+ReLU ----------------
// hw = bf16(relu(sc*h + sh)) @ W   (aff=0: plain h @ W, no relu)
__global__ __launch_bounds__(256) void k_gemm(const float* __restrict__ hf,
                                              const ushort* __restrict__ wt,   // [n][k] bf16
                                              const float* __restrict__ sc, const float* __restrict__ sh,
                                              const int aff,
                                              ushort* __restrict__ hw) {
  __shared__ ushort wlds[128 * 128];                 // 32 KiB
  __shared__ float scs[128], shs[128];
  const int t = threadIdx.x;
  {
    const uint4* src = (const uint4*)wt;
    uint4* dst = (uint4*)wlds;
    #pragma unroll
    for (int i = 0; i < 8; ++i) {
      int idx = t + i * 256;
      int n = idx >> 4;
      dst[idx ^ (n & 7)] = src[idx];
    }
  }
  if (t < 128) { scs[t] = aff ? sc[t] : 1.0f; shs[t] = aff ? sh[t] : 0.0f; }
  __syncthreads();

  const int wv = t >> 6, l = t & 63;
  const int lr = l & 15, lk = l >> 4;
  const int row0 = blockIdx.x * 128 + wv * 32;
  f32x4 acc[2][8] = {};
  const uint4* wchunks = (const uint4*)wlds;

  #pragma unroll
  for (int kb = 0; kb < 4; ++kb) {
    const int k0 = kb * 32 + lk * 8;
    const float4 s4a = *(const float4*)(scs + k0);
    const float4 s4b = *(const float4*)(scs + k0 + 4);
    const float4 h4a = *(const float4*)(shs + k0);
    const float4 h4b = *(const float4*)(shs + k0 + 4);
    const int r0 = min(row0 + lr, NN - 1);
    const int r1 = min(row0 + 16 + lr, NN - 1);
    bf16x8 a0, a1;
    #pragma unroll
    for (int rr = 0; rr < 2; ++rr) {
      const int r = rr ? r1 : r0;
      const float4 p = *(const float4*)(hf + (size_t)r * 128 + k0);
      const float4 q = *(const float4*)(hf + (size_t)r * 128 + k0 + 4);
      float u0 = fmaf(s4a.x, p.x, h4a.x), u1 = fmaf(s4a.y, p.y, h4a.y);
      float u2 = fmaf(s4a.z, p.z, h4a.z), u3 = fmaf(s4a.w, p.w, h4a.w);
      float u4 = fmaf(s4b.x, q.x, h4b.x), u5 = fmaf(s4b.y, q.y, h4b.y);
      float u6 = fmaf(s4b.z, q.z, h4b.z), u7 = fmaf(s4b.w, q.w, h4b.w);
      if (aff) {
        u0 = fmaxf(u0, 0.f); u1 = fmaxf(u1, 0.f); u2 = fmaxf(u2, 0.f); u3 = fmaxf(u3, 0.f);
        u4 = fmaxf(u4, 0.f); u5 = fmaxf(u5, 0.f); u6 = fmaxf(u6, 0.f); u7 = fmaxf(u7, 0.f);
      }
      bf16x8 a;
      a[0] = (short)f2b(u0); a[1] = (short)f2b(u1); a[2] = (short)f2b(u2); a[3] = (short)f2b(u3);
      a[4] = (short)f2b(u4); a[5] = (short)f2b(u5); a[6] = (short)f2b(u6); a[7] = (short)f2b(u7);
      if (rr) a1 = a; else a0 = a;
    }
    #pragma unroll
    for (int nt = 0; nt < 8; ++nt) {
      const int n = nt * 16 + lr;
      const int chunk = n * 16 + ((kb * 4 + lk) ^ (n & 7));
      const bf16x8 b = *(const bf16x8*)(wchunks + chunk);
      acc[0][nt] = __builtin_amdgcn_mfma_f32_16x16x32_bf16(a0, b, acc[0][nt], 0, 0, 0);
      acc[1][nt] = __builtin_amdgcn_mfma_f32_16x16x32_bf16(a1, b, acc[1][nt], 0, 0, 0);
    }
  }
  #pragma unroll
  for (int rt = 0; rt < 2; ++rt)
    #pragma unroll
    for (int j = 0; j < 4; ++j) {
      const int row = row0 + rt * 16 + lk * 4 + j;
      if (row < NN) {
        #pragma unroll
        for (int nt = 0; nt < 8; ++nt)
          hw[(size_t)row * 128 + nt * 16 + lr] = f2b(acc[rt][nt][j]);
      }
    }
}

// ---------------- aggregation (r3-proven shape: one wave/node, plain cached loads) ----------------
// lane owns 2 features (uint = 2 bf16, 256B/row per wave); unroll 8 -> 8 rows in flight.
__global__ __launch_bounds__(256) void k_agg(const ushort* __restrict__ hw,
                                             const int* __restrict__ rp, const int* __restrict__ csr,
                                             const float* __restrict__ dinv, const float* __restrict__ bias,
                                             float* __restrict__ out) {
  const int wid = (blockIdx.x * 256 + threadIdx.x) >> 6;
  const int lane = threadIdx.x & 63;
  const int v = wid;                                 // grid covers NN exactly (25000*4 waves)
  const int beg = rp[v], end = rp[v + 1];
  float ax = 0.f, ay = 0.f;
  int i = beg;
  for (; i + 8 <= end; i += 8) {
    int s[8]; float dd[8]; uint w[8];
    #pragma unroll
    for (int j = 0; j < 8; ++j) s[j] = csr[i + j];
    #pragma unroll
    for (int j = 0; j < 8; ++j) dd[j] = dinv[s[j]];
    #pragma unroll
    for (int j = 0; j < 8; ++j) w[j] = *(const uint*)(hw + (size_t)s[j] * 128 + 2 * lane);
    #pragma unroll
    for (int j = 0; j < 8; ++j) {
      ax = fmaf(dd[j], blo(w[j]), ax);
      ay = fmaf(dd[j], bhi(w[j]), ay);
    }
  }
  for (; i + 4 <= end; i += 4) {
    const int s0 = csr[i], s1 = csr[i + 1], s2 = csr[i + 2], s3 = csr[i + 3];
    const float d0 = dinv[s0], d1 = dinv[s1], d2 = dinv[s2], d3 = dinv[s3];
    const uint v0 = *(const uint*)(hw + (size_t)s0 * 128 + 2 * lane);
    const uint v1 = *(const uint*)(hw + (size_t)s1 * 128 + 2 * lane);
    const uint v2 = *(const uint*)(hw + (size_t)s2 * 128 + 2 * lane);
    const uint v3 = *(const uint*)(hw + (size_t)s3 * 128 + 2 * lane);
    ax = fmaf(d0, blo(v0), ax); ay = fmaf(d0, bhi(v0), ay);
    ax = fmaf(d1, blo(v1), ax); ay = fmaf(d1, bhi(v1), ay);
    ax = fmaf(d2, blo(v2), ax); ay = fmaf(d2, bhi(v2), ay);
    ax = fmaf(d3, blo(v3), ax); ay = fmaf(d3, bhi(v3), ay);
  }
  for (; i < end; ++i) {
    const int s = csr[i];
    const float ds = dinv[s];
    const uint vv = *(const uint*)(hw + (size_t)s * 128 + 2 * lane);
    ax = fmaf(ds, blo(vv), ax); ay = fmaf(ds, bhi(vv), ay);
  }
  const float dv = dinv[v];
  const uint sv = *(const uint*)(hw + (size_t)v * 128 + 2 * lane);
  const float bx = bias[2 * lane], by = bias[2 * lane + 1];
  float2 o;
  o.x = fmaf(ax, dv, fmaf(blo(sv), dv * dv, bx));
  o.y = fmaf(ay, dv, fmaf(bhi(sv), dv * dv, by));
  *(float2*)(out + (size_t)v * 128 + 2 * lane) = o;
}

// ---------------- BatchNorm stats (separate streaming pass — ~15us, proven) ----------------
__global__ __launch_bounds__(256) void k_bnstats(const float* __restrict__ h, float* __restrict__ stats) {
  __shared__ float rs[256], rs2[256];
  const int t = threadIdx.x;
  const int col = t & 127, rg = t >> 7;
  const int row0 = blockIdx.x * 128;
  const int rend = min(row0 + 128, NN);
  float s = 0.f, s2 = 0.f;
  for (int r = row0 + rg; r < rend; r += 2) {
    float v = h[(size_t)r * 128 + col];
    s += v;
    s2 = fmaf(v, v, s2);
  }
  rs[t] = s; rs2[t] = s2;
  __syncthreads();
  if (t < 128) {
    atomicAdd(&stats[t], rs[t] + rs[t + 128]);
    atomicAdd(&stats[128 + t], rs2[t] + rs2[t + 128]);
  }
}

__global__ void k_bnfin(const float* __restrict__ stats, const float* __restrict__ gamma,
                        const float* __restrict__ beta, float* __restrict__ sc, float* __restrict__ sh) {
  const int c = threadIdx.x;
  const float inv_n = 1.0f / (float)NN;
  const float mean = stats[c] * inv_n;
  const float var = fmaxf(stats[128 + c] * inv_n - mean * mean, 0.f);
  const float k = gamma[c] * rsqrtf(var + BN_EPS);
  sc[c] = k;
  sh[c] = fmaf(-mean, k, beta[c]);
}

// final layer only: BN+relu in place on fp32 output
__global__ __launch_bounds__(256) void k_bnfinal(float* __restrict__ h,
                                                 const float* __restrict__ sc, const float* __restrict__ sh) {
  const int i = blockIdx.x * 256 + threadIdx.x;      // grid covers NN*128/4 exactly
  const int c = (i & 31) * 4;
  float4 v = ((const float4*)h)[i];
  v.x = fmaxf(fmaf(sc[c + 0], v.x, sh[c + 0]), 0.f);
  v.y = fmaxf(fmaf(sc[c + 1], v.y, sh[c + 1]), 0.f);
  v.z = fmaxf(fmaf(sc[c + 2], v.z, sh[c + 2]), 0.f);
  v.w = fmaxf(fmaf(sc[c + 3], v.w, sh[c + 3]), 0.f);
  ((float4*)h)[i] = v;
}

// ---------------- launch ----------------
extern "C" void kernel_launch(void* const* d_in, const int* in_sizes, int n_in,
                              void* d_out, int out_size, void* d_ws, size_t ws_size,
                              hipStream_t stream) {
  const float* x  = (const float*)d_in[0];
  const int*   ei = (const int*)d_in[1];
  const float* W[3]  = {(const float*)d_in[2],  (const float*)d_in[6],  (const float*)d_in[10]};
  const float* b[3]  = {(const float*)d_in[3],  (const float*)d_in[7],  (const float*)d_in[11]};
  const float* g[3]  = {(const float*)d_in[4],  (const float*)d_in[8],  (const float*)d_in[12]};
  const float* be[3] = {(const float*)d_in[5],  (const float*)d_in[9],  (const float*)d_in[13]};

  char* ws = (char*)d_ws;
  ushort* hwb    = (ushort*)(ws);               // NN*128 bf16 = 25,600,000 B
  uint*   binned = (uint*)(ws);                 // overlay: 8*NBKT*BCAP*4 = 12,812,288 B (dead before gemm)
  int*    bfill  = (int*)(ws + 13000000);       // 8*NBKT*4 = 25,024 B (dead before gemm)
  int*    csr    = (int*)(ws + 51200000);       // NE ints
  int*    deg    = (int*)(ws + 57600000);
  int*    rp     = (int*)(ws + 58000000);
  float*  dinv   = (float*)(ws + 58400016);
  ushort* wtb    = (ushort*)(ws + 58800016);    // 3 x 128x128 bf16 (W^T)
  float*  stats  = (float*)(ws + 58898320);
  float*  sc     = (float*)(ws + 58899344);
  float*  sh     = (float*)(ws + 58899856);
  int*    bsum   = (int*)(ws + 58900368);       // NB ints
  int*    boff   = (int*)(ws + 58901936);       // NB ints
  float*  hbuf   = (float*)d_out;               // fp32 agg output (pre-BN), also final output

  hipMemsetAsync(deg, 0, NN * 4, stream);
  hipMemsetAsync(bfill, 0, 8 * NBKT * 4, stream);
  k_bin<<<NE / 256, 256, 0, stream>>>(ei, deg, bfill, binned);
  k_dinv<<<(NN + 255) / 256, 256, 0, stream>>>(deg, dinv);
  k_scan1<<<NB, 256, 0, stream>>>(deg, bsum);
  k_scan2<<<1, 512, 0, stream>>>(bsum, boff, rp);
  k_scan3<<<NB, 256, 0, stream>>>(deg, boff, rp);
  k_scatter2<<<NBKT, 256, 0, stream>>>(binned, bfill, rp, csr);
  k_wt<<<dim3(128, 3), 128, 0, stream>>>(W[0], W[1], W[2], wtb);

  for (int L = 0; L < 3; ++L) {
    const float* hin = (L == 0) ? x : hbuf;
    k_gemm<<<(NN + 127) / 128, 256, 0, stream>>>(hin, wtb + L * 16384, sc, sh, (L > 0) ? 1 : 0, hwb);
    k_agg<<<25000, 256, 0, stream>>>(hwb, rp, csr, dinv, b[L], hbuf);
    hipMemsetAsync(stats, 0, 256 * 4, stream);
    k_bnstats<<<(NN + 127) / 128, 256, 0, stream>>>(hbuf, stats);
    k_bnfin<<<1, 128, 0, stream>>>(stats, g[L], be[L], sc, sh);
  }
  k_bnfinal<<<NN * 128 / 1024, 256, 0, stream>>>(hbuf, sc, sh);
}